// Round 2
// baseline (155.660 us; speedup 1.0000x reference)
//
#include <hip/hip_runtime.h>
#include <stdint.h>

#define BATCH 128
#define HH 14
#define WW 14
#define CC 512
#define HW (HH * WW)      // 196
#define KM_ITERS 10       // reference runs ITERS+1 = 11 assignment steps

// ---------------------------------------------------------------------------
// Kernel 1: per (b,c) find (arg1 = w of max, arg0 = h of max) with numpy's
// first-index tie semantics for BOTH independent argmaxes.
// Block = one batch b, thread = channel c (coalesced: fixed pixel, c varies).
// ---------------------------------------------------------------------------
__global__ __launch_bounds__(512) void k_points(const float* __restrict__ x,
                                                float2* __restrict__ pts) {
    const int b = blockIdx.x;
    const int c = threadIdx.x;
    const float* base = x + (size_t)b * HW * CC + c;

    float colmax[WW];
#pragma unroll
    for (int w = 0; w < WW; ++w) colmax[w] = -INFINITY;

    float best = -INFINITY;
    int arg0 = 0;
    for (int h = 0; h < HH; ++h) {
        float rowmax = -INFINITY;
#pragma unroll
        for (int w = 0; w < WW; ++w) {
            float v = base[(size_t)(h * WW + w) * CC];
            rowmax = fmaxf(rowmax, v);
            colmax[w] = fmaxf(colmax[w], v);
        }
        if (rowmax > best) { best = rowmax; arg0 = h; }  // strict > keeps first h
    }
    int arg1 = -1;
#pragma unroll
    for (int w = 0; w < WW; ++w) {
        if (arg1 < 0 && colmax[w] == best) arg1 = w;      // first w attaining max
    }
    pts[b * CC + c] = make_float2((float)arg1, (float)arg0);
}

// ---------------------------------------------------------------------------
// Kernel 2: k-means, K=2, 11 assignment steps with the reference's swapped
// centroid update (c0 <- mean of assign==1, c1 <- mean of assign==0).
// One wave (64 lanes) per batch; each lane owns 8 points (c = lane + 64*j).
// All sums are integer-valued => exact in fp32 regardless of order.
// Distances use _rn intrinsics so no FMA contraction (must match numpy's
// mul,mul,add rounding: one flipped compare = wrong output).
// ---------------------------------------------------------------------------
__global__ __launch_bounds__(64) void k_kmeans(const float2* __restrict__ pts,
                                               uint8_t* __restrict__ assign) {
    const int b = blockIdx.x;
    const int lane = threadIdx.x;

    float px[8], py[8];
#pragma unroll
    for (int j = 0; j < 8; ++j) {
        float2 p = pts[b * CC + lane + 64 * j];
        px[j] = p.x; py[j] = p.y;
    }

    // totals over all 512 points (exact integers)
    float totx = 0.f, toty = 0.f;
#pragma unroll
    for (int j = 0; j < 8; ++j) { totx += px[j]; toty += py[j]; }
#pragma unroll
    for (int s = 32; s >= 1; s >>= 1) {
        totx += __shfl_xor(totx, s);
        toty += __shfl_xor(toty, s);
    }

    // initial centroids = points of channels 0 and 1
    float c0x = __shfl(px[0], 0), c0y = __shfl(py[0], 0);
    float c1x = __shfl(px[0], 1), c1y = __shfl(py[0], 1);

    int a[8];
    for (int it = 0; it <= KM_ITERS; ++it) {
        float sx = 0.f, sy = 0.f, cnt = 0.f;
#pragma unroll
        for (int j = 0; j < 8; ++j) {
            float dx0 = __fsub_rn(px[j], c0x);
            float dy0 = __fsub_rn(py[j], c0y);
            float d0  = __fadd_rn(__fmul_rn(dx0, dx0), __fmul_rn(dy0, dy0));
            float dx1 = __fsub_rn(px[j], c1x);
            float dy1 = __fsub_rn(py[j], c1y);
            float d1  = __fadd_rn(__fmul_rn(dx1, dx1), __fmul_rn(dy1, dy1));
            a[j] = (d1 < d0) ? 1 : 0;   // argmin: tie -> cluster 0
            if (a[j]) { sx += px[j]; sy += py[j]; cnt += 1.f; }
        }
#pragma unroll
        for (int s = 32; s >= 1; s >>= 1) {
            sx  += __shfl_xor(sx, s);
            sy  += __shfl_xor(sy, s);
            cnt += __shfl_xor(cnt, s);
        }
        float cnt0 = (float)CC - cnt;           // exact
        c0x = __fdiv_rn(sx, fmaxf(cnt, 1.f));   // note the swap: c0 from m1
        c0y = __fdiv_rn(sy, fmaxf(cnt, 1.f));
        c1x = __fdiv_rn(totx - sx, fmaxf(cnt0, 1.f));  // exact int subtraction
        c1y = __fdiv_rn(toty - sy, fmaxf(cnt0, 1.f));
    }

#pragma unroll
    for (int j = 0; j < 8; ++j)
        assign[b * CC + lane + 64 * j] = (uint8_t)a[j];
}

// ---------------------------------------------------------------------------
// Kernel 3: scatter. One thread per float4 (4 channels). Mask loaded as one
// uint32 (4 assignment bytes). Writes C0 then C1 (concatenated in d_out).
// ---------------------------------------------------------------------------
#define N4 (BATCH * HW * (CC / 4))   // 3,211,264 float4 per output

__global__ __launch_bounds__(256) void k_scatter(const float4* __restrict__ x4,
                                                 const uint32_t* __restrict__ am4,
                                                 float4* __restrict__ out4) {
    const int idx = blockIdx.x * 256 + threadIdx.x;
    if (idx >= N4) return;
    const int c4  = idx & (CC / 4 - 1);   // 0..127
    const int pix = idx >> 7;             // b*196 + hw
    const int b   = pix / HW;

    const uint32_t m = am4[b * (CC / 4) + c4];
    const float4 v = x4[idx];

    float4 o0, o1;
    o0.x = (m & 0x000000ffu) ? 0.f : v.x;  o1.x = (m & 0x000000ffu) ? v.x : 0.f;
    o0.y = (m & 0x0000ff00u) ? 0.f : v.y;  o1.y = (m & 0x0000ff00u) ? v.y : 0.f;
    o0.z = (m & 0x00ff0000u) ? 0.f : v.z;  o1.z = (m & 0x00ff0000u) ? v.z : 0.f;
    o0.w = (m & 0xff000000u) ? 0.f : v.w;  o1.w = (m & 0xff000000u) ? v.w : 0.f;

    out4[idx]      = o0;   // C0
    out4[idx + N4] = o1;   // C1
}

// ---------------------------------------------------------------------------
extern "C" void kernel_launch(void* const* d_in, const int* in_sizes, int n_in,
                              void* d_out, int out_size, void* d_ws, size_t ws_size,
                              hipStream_t stream) {
    const float* x = (const float*)d_in[0];

    float2*  pts    = (float2*)d_ws;                                        // 512 KiB
    uint8_t* assign = (uint8_t*)d_ws + (size_t)BATCH * CC * sizeof(float2); // 64 KiB

    k_points<<<BATCH, 512, 0, stream>>>(x, pts);
    k_kmeans<<<BATCH, 64, 0, stream>>>(pts, assign);
    k_scatter<<<(N4 + 255) / 256, 256, 0, stream>>>(
        (const float4*)x, (const uint32_t*)assign, (float4*)d_out);
}